// Round 4
// baseline (7544.306 us; speedup 1.0000x reference)
//
#include <hip/hip_runtime.h>
#include <math.h>

typedef float f4u __attribute__((ext_vector_type(4), aligned(4)));
typedef float nfloat4 __attribute__((ext_vector_type(4), aligned(16)));

__device__ __forceinline__ float softsign(float v) {
    float d = 1.0f + fabsf(v);
    return v * __builtin_amdgcn_rcpf(d);
}
__device__ __forceinline__ void nt_store4(float* p, float a, float b, float c, float d) {
    nfloat4 v; v.x = a; v.y = b; v.z = c; v.w = d;
    __builtin_nontemporal_store(v, (nfloat4*)p);
}
__device__ __forceinline__ int clamp63(int v) { return v < 0 ? 0 : (v > 63 ? 63 : v); }

__device__ __forceinline__ void load_row6(const float* __restrict__ row, int x0, float r[6]) {
    const float4 v = *(const float4*)(row + x0);
    r[0] = row[x0 == 0 ? 0 : x0 - 1];
    r[1] = v.x; r[2] = v.y; r[3] = v.z; r[4] = v.w;
    r[5] = row[x0 == 60 ? 63 : x0 + 4];
}

// -------- first layer: 2 input channels -> 1 channel (round-0 verbatim) --------
__global__ __launch_bounds__(256) void conv_first(const float* __restrict__ in0,
                                                  const float* __restrict__ in1,
                                                  float* __restrict__ out,
                                                  const float* __restrict__ w,
                                                  const float* __restrict__ bias) {
    int tid = blockIdx.x * 256 + threadIdx.x;
    int xq = (tid & 15) << 2;
    int y  = (tid >> 4) & 63;
    int z0 = ((tid >> 10) & 15) << 2;
    int b  = tid >> 14;
    const float* base0 = in0 + (size_t)b * 262144;
    const float* base1 = in1 + (size_t)b * 262144;

    float acc[4][4];
    #pragma unroll
    for (int i = 0; i < 4; ++i)
        #pragma unroll
        for (int j = 0; j < 4; ++j) acc[i][j] = 0.0f;

    #pragma unroll
    for (int zi = 0; zi < 6; ++zi) {
        int zin = clamp63(z0 + zi - 1);
        const float* p0 = base0 + zin * 4096;
        const float* p1 = base1 + zin * 4096;
        #pragma unroll
        for (int dy = 0; dy < 3; ++dy) {
            int yin = clamp63(y + dy - 1);
            float r0[6], r1[6];
            load_row6(p0 + yin * 64, xq, r0);
            load_row6(p1 + yin * 64, xq, r1);
            #pragma unroll
            for (int dz = 0; dz < 3; ++dz) {
                int zo = zi - dz;
                if (zo >= 0 && zo < 4) {
                    #pragma unroll
                    for (int dx = 0; dx < 3; ++dx) {
                        float w0v = w[dz * 9 + dy * 3 + dx];
                        float w1v = w[27 + dz * 9 + dy * 3 + dx];
                        #pragma unroll
                        for (int xx = 0; xx < 4; ++xx) {
                            acc[zo][xx] = fmaf(w0v, r0[xx + dx], acc[zo][xx]);
                            acc[zo][xx] = fmaf(w1v, r1[xx + dx], acc[zo][xx]);
                        }
                    }
                }
            }
        }
    }
    float bv = *bias;
    float* obase = out + (size_t)b * 262144 + (size_t)z0 * 4096 + y * 64 + xq;
    #pragma unroll
    for (int zo = 0; zo < 4; ++zo) {
        float4 o;
        o.x = softsign(acc[zo][0] + bv);
        o.y = softsign(acc[zo][1] + bv);
        o.z = softsign(acc[zo][2] + bv);
        o.w = softsign(acc[zo][3] + bv);
        *(float4*)(obase + zo * 4096) = o;
    }
}

// ---- manual grid barrier (device-scope, graph-capture-safe) ----
// Generation barrier on __device__ globals: count returns to 0 after every
// completed barrier, gen grows monotonically -> safe across repeated timed
// launches with no per-launch init. Spin uses RELAXED loads (an acquire load
// per poll would buffer_inv the local L2 every iteration); one acquire fence
// (__threadfence) after exit provides the cross-XCD visibility.
#define NBLK 512
__device__ unsigned g_bar_count = 0;
__device__ unsigned g_bar_gen   = 0;

__device__ __forceinline__ void grid_barrier() {
    __syncthreads();
    if (threadIdx.x == 0) {
        __threadfence();   // release: drain + write back our tile's stores
        unsigned gen = __hip_atomic_load(&g_bar_gen, __ATOMIC_RELAXED, __HIP_MEMORY_SCOPE_AGENT);
        unsigned prev = __hip_atomic_fetch_add(&g_bar_count, 1u, __ATOMIC_ACQ_REL, __HIP_MEMORY_SCOPE_AGENT);
        if (prev == NBLK - 1u) {
            __hip_atomic_store(&g_bar_count, 0u, __ATOMIC_RELAXED, __HIP_MEMORY_SCOPE_AGENT);
            __hip_atomic_fetch_add(&g_bar_gen, 1u, __ATOMIC_RELEASE, __HIP_MEMORY_SCOPE_AGENT);
        } else {
            while (__hip_atomic_load(&g_bar_gen, __ATOMIC_RELAXED, __HIP_MEMORY_SCOPE_AGENT) == gen)
                __builtin_amdgcn_s_sleep(2);
        }
        __threadfence();   // acquire: invalidate stale L1/L2 before next layer's reads
    }
    __syncthreads();
}

// ---- persistent middle layers: round-0 conv_mid body looped 100x ----
// Per block: 64x * 16y * 8z outputs, thread = 8z*1y*4x. LDS: 48.96 KB staging +
// 11.2 KB weights = 60.2 KB -> exactly 2 blocks/CU (launch_bounds(256,2)), so
// the 512-block grid is fully co-resident and the manual barrier cannot deadlock.
// Grid 512 = 8 z-slabs (XCD-affine via blk&7) x 16 batches x 4 y-tiles.
#define LROW   68
#define LPLANE 1224   // 18*68

__global__ __launch_bounds__(256, 2) void conv_mid_persist(const float* __restrict__ buf0,
                                                           float* __restrict__ buf1,
                                                           const float* __restrict__ wsp,
                                                           const float* __restrict__ bsp) {
    __shared__ float lds[10 * LPLANE];
    __shared__ float wAll[2700];
    __shared__ float bAll[100];

    int blk = blockIdx.x;
    int xcd = blk & 7;
    int j   = blk >> 3;                // 0..63
    int b   = j & 15;
    int y0  = ((j >> 4) & 3) << 4;     // 0,16,32,48
    int z0  = xcd << 3;                // XCD-affine z-slab

    int t = threadIdx.x;
    int l = t & 15;
    int g = t >> 4;

    // stage all weights/biases into LDS once (they survive barriers)
    for (int i = t; i < 2700; i += 256) wAll[i] = wsp[i];
    for (int i = t; i < 100; i += 256) bAll[i] = bsp[i];
    // first use is after layer-0's staging __syncthreads -> covered

    const size_t bofs = (size_t)b * 262144;
    const float* src = buf0;
    float*       dst = buf1;

    #pragma unroll 1
    for (int L = 0; L < 100; ++L) {
        const float* base = src + bofs;

        // ---- stage 180 rows (10 planes x 18 rows); round-0 verbatim ----
        {
            int off = (l == 0) ? 0 : (4 * l - 1);
            #pragma unroll
            for (int half = 0; half < 2; ++half) {
                float* lrows[6];
                f4u mv[6];
                float tv[6];
                #pragma unroll
                for (int it = 0; it < 6; ++it) {
                    int rid = (half * 6 + it) * 16 + g;      // 0..191 (180..191 dummy)
                    int pa = rid / 18;
                    pa = pa > 9 ? 9 : pa;                     // dummy rows: clamp-safe addr
                    int pr = rid - pa * 18;
                    pr = pr > 17 ? 17 : pr;
                    const float* grow = base + clamp63(z0 - 1 + pa) * 4096 + clamp63(y0 - 1 + pr) * 64;
                    lrows[it] = &lds[pa * LPLANE + pr * LROW];
                    mv[it] = *(const f4u*)(grow + off);
                    tv[it] = grow[63];
                }
                #pragma unroll
                for (int it = 0; it < 6; ++it) {
                    int rid = (half * 6 + it) * 16 + g;
                    if (rid < 180) {
                        if (l == 0)
                            *(float4*)lrows[it] = (float4){mv[it].x, mv[it].x, mv[it].y, mv[it].z};
                        else
                            *(float4*)(lrows[it] + 4 * l) = (float4){mv[it].x, mv[it].y, mv[it].z, mv[it].w};
                        if (l == 15)
                            *(float2*)(lrows[it] + 64) = (float2){tv[it], tv[it]};
                    }
                }
            }
        }
        __syncthreads();

        // ---- per-layer weights from LDS (broadcast reads) ----
        float wv[27];
        #pragma unroll
        for (int i = 0; i < 27; ++i) wv[i] = wAll[L * 27 + i];
        float bv = bAll[L];

        // ---- compute: 8z x 1y x 4x per thread; round-0 verbatim ----
        int xq   = l << 2;
        int yloc = g;          // 0..15; LDS rows yloc..yloc+2 = y-1,y,y+1

        float acc[8][4];
        #pragma unroll
        for (int i = 0; i < 8; ++i)
            #pragma unroll
            for (int jj = 0; jj < 4; ++jj) acc[i][jj] = 0.0f;

        #pragma unroll
        for (int zi = 0; zi < 10; ++zi) {
            const float* pl = &lds[zi * LPLANE];
            #pragma unroll
            for (int dy = 0; dy < 3; ++dy) {
                const float* lrow = pl + (yloc + dy) * LROW;
                const float4 v  = *(const float4*)(lrow + xq);
                const float2 v2 = *(const float2*)(lrow + xq + 4);
                float r[6] = {v.x, v.y, v.z, v.w, v2.x, v2.y};
                #pragma unroll
                for (int dz = 0; dz < 3; ++dz) {
                    int zo = zi - dz;   // out z offset; planes zo..zo+2 feed it
                    if (zo >= 0 && zo < 8) {
                        #pragma unroll
                        for (int dx = 0; dx < 3; ++dx) {
                            float ww = wv[dz * 9 + dy * 3 + dx];
                            #pragma unroll
                            for (int xx = 0; xx < 4; ++xx)
                                acc[zo][xx] = fmaf(ww, r[xx + dx], acc[zo][xx]);
                        }
                    }
                }
            }
        }

        int y = y0 + yloc;
        float* obase = dst + bofs + (size_t)z0 * 4096 + y * 64 + xq;
        #pragma unroll
        for (int zo = 0; zo < 8; ++zo) {
            float4 o;
            o.x = softsign(acc[zo][0] + bv);
            o.y = softsign(acc[zo][1] + bv);
            o.z = softsign(acc[zo][2] + bv);
            o.w = softsign(acc[zo][3] + bv);
            *(float4*)(obase + zo * 4096) = o;
        }

        // ping-pong swap; device-wide barrier before next layer's staging reads
        const float* ns = dst;
        dst = (float*)src;
        src = ns;
        if (L != 99) grid_barrier();
    }
}

// -------- last layer: 1 -> 3 channels + strided downsample outputs (round-0 verbatim) --------
__global__ __launch_bounds__(256) void conv_last(const float* __restrict__ in,
                                                 float* __restrict__ out,
                                                 const float* __restrict__ w,
                                                 const float* __restrict__ bias) {
    int tid = blockIdx.x * 256 + threadIdx.x;
    int xq = (tid & 15) << 2;
    int y  = (tid >> 4) & 63;
    int z0 = ((tid >> 10) & 15) << 2;
    int b  = tid >> 14;
    const float* base = in + (size_t)b * 262144;

    float acc[4][3][4];
    #pragma unroll
    for (int i = 0; i < 4; ++i)
        #pragma unroll
        for (int c = 0; c < 3; ++c)
            #pragma unroll
            for (int j = 0; j < 4; ++j) acc[i][c][j] = 0.0f;

    #pragma unroll
    for (int zi = 0; zi < 6; ++zi) {
        int zin = clamp63(z0 + zi - 1);
        const float* plane = base + zin * 4096;
        #pragma unroll
        for (int dy = 0; dy < 3; ++dy) {
            int yin = clamp63(y + dy - 1);
            float r[6];
            load_row6(plane + yin * 64, xq, r);
            #pragma unroll
            for (int dz = 0; dz < 3; ++dz) {
                int zo = zi - dz;
                if (zo >= 0 && zo < 4) {
                    #pragma unroll
                    for (int c = 0; c < 3; ++c) {
                        #pragma unroll
                        for (int dx = 0; dx < 3; ++dx) {
                            float wc = w[c * 27 + dz * 9 + dy * 3 + dx];
                            #pragma unroll
                            for (int xx = 0; xx < 4; ++xx)
                                acc[zo][c][xx] = fmaf(wc, r[xx + dx], acc[zo][c][xx]);
                        }
                    }
                }
            }
        }
    }

    float* r64 = out;
    float* r32 = out + 12582912;
    float* r16 = r32 + 1572864;
    float* r8  = r16 + 196608;

    float vals[4][3][4];
    #pragma unroll
    for (int zo = 0; zo < 4; ++zo)
        #pragma unroll
        for (int c = 0; c < 3; ++c) {
            float bv = bias[c];
            #pragma unroll
            for (int xx = 0; xx < 4; ++xx)
                vals[zo][c][xx] = softsign(acc[zo][c][xx] + bv);
        }

    #pragma unroll
    for (int c = 0; c < 3; ++c) {
        float* cb = r64 + ((size_t)b * 3 + c) * 262144 + (size_t)z0 * 4096 + y * 64 + xq;
        #pragma unroll
        for (int zo = 0; zo < 4; ++zo) {
            nt_store4(cb + zo * 4096,
                      vals[zo][c][0], vals[zo][c][1], vals[zo][c][2], vals[zo][c][3]);
        }
    }
    if ((y & 1) == 0) {
        #pragma unroll
        for (int c = 0; c < 3; ++c) {
            size_t cb = ((size_t)b * 3 + c) * 32768 + (size_t)(y >> 1) * 32;
            #pragma unroll
            for (int zo = 0; zo < 4; zo += 2) {
                size_t zb = cb + (size_t)((z0 + zo) >> 1) * 1024;
                __builtin_nontemporal_store(vals[zo][c][0], r32 + zb + ((xq + 0) >> 1));
                __builtin_nontemporal_store(vals[zo][c][2], r32 + zb + ((xq + 2) >> 1));
            }
        }
    }
    if ((y & 3) == 0) {
        #pragma unroll
        for (int c = 0; c < 3; ++c) {
            __builtin_nontemporal_store(vals[0][c][0],
                r16 + ((size_t)b * 3 + c) * 4096 + (size_t)(z0 >> 2) * 256 + (y >> 2) * 16 + (xq >> 2));
        }
    }
    if ((y & 7) == 0 && (z0 & 7) == 0 && (xq & 7) == 0) {
        #pragma unroll
        for (int c = 0; c < 3; ++c) {
            __builtin_nontemporal_store(vals[0][c][0],
                r8 + ((size_t)b * 3 + c) * 512 + (size_t)(z0 >> 3) * 64 + (y >> 3) * 8 + (xq >> 3));
        }
    }
}

extern "C" void kernel_launch(void* const* d_in, const int* in_sizes, int n_in,
                              void* d_out, int out_size, void* d_ws, size_t ws_size,
                              hipStream_t stream) {
    const float* preop = (const float*)d_in[0];
    const float* intra = (const float*)d_in[1];
    const float* w0    = (const float*)d_in[2];
    const float* b0p   = (const float*)d_in[3];
    const float* wsp   = (const float*)d_in[4];
    const float* bsp   = (const float*)d_in[5];
    const float* wX    = (const float*)d_in[6];
    const float* bX    = (const float*)d_in[7];
    float* out = (float*)d_out;

    float* buf0 = (float*)d_ws;
    float* buf1 = out;   // ping-pong scratch inside the (larger) output buffer

    conv_first<<<dim3(1024), dim3(256), 0, stream>>>(preop, intra, buf0, w0, b0p);

    // 100 mid layers in ONE persistent kernel (plain launch, manual grid barrier).
    // Layer L reads (L even ? buf0 : buf1), writes the other; layer 99 -> buf0.
    conv_mid_persist<<<dim3(NBLK), dim3(256), 0, stream>>>(buf0, buf1, wsp, bsp);

    conv_last<<<dim3(1024), dim3(256), 0, stream>>>(buf0, out, wX, bX);
}

// Round 7
// 1167.167 us; speedup vs baseline: 6.4638x; 6.4638x over previous
//
#include <hip/hip_runtime.h>
#include <math.h>

typedef float f4u __attribute__((ext_vector_type(4), aligned(4)));
typedef float nfloat4 __attribute__((ext_vector_type(4), aligned(16)));

__device__ __forceinline__ float softsign(float v) {
    float d = 1.0f + fabsf(v);
    return v * __builtin_amdgcn_rcpf(d);
}
__device__ __forceinline__ void nt_store4(float* p, float a, float b, float c, float d) {
    nfloat4 v; v.x = a; v.y = b; v.z = c; v.w = d;
    __builtin_nontemporal_store(v, (nfloat4*)p);
}
__device__ __forceinline__ int clamp63(int v) { return v < 0 ? 0 : (v > 63 ? 63 : v); }

__device__ __forceinline__ void load_row6(const float* __restrict__ row, int x0, float r[6]) {
    const float4 v = *(const float4*)(row + x0);
    r[0] = row[x0 == 0 ? 0 : x0 - 1];
    r[1] = v.x; r[2] = v.y; r[3] = v.z; r[4] = v.w;
    r[5] = row[x0 == 60 ? 63 : x0 + 4];
}

// -------- first layer: 2 input channels -> 1 channel (round-0 verbatim) --------
__global__ __launch_bounds__(256) void conv_first(const float* __restrict__ in0,
                                                  const float* __restrict__ in1,
                                                  float* __restrict__ out,
                                                  const float* __restrict__ w,
                                                  const float* __restrict__ bias) {
    int tid = blockIdx.x * 256 + threadIdx.x;
    int xq = (tid & 15) << 2;
    int y  = (tid >> 4) & 63;
    int z0 = ((tid >> 10) & 15) << 2;
    int b  = tid >> 14;
    const float* base0 = in0 + (size_t)b * 262144;
    const float* base1 = in1 + (size_t)b * 262144;

    float acc[4][4];
    #pragma unroll
    for (int i = 0; i < 4; ++i)
        #pragma unroll
        for (int j = 0; j < 4; ++j) acc[i][j] = 0.0f;

    #pragma unroll
    for (int zi = 0; zi < 6; ++zi) {
        int zin = clamp63(z0 + zi - 1);
        const float* p0 = base0 + zin * 4096;
        const float* p1 = base1 + zin * 4096;
        #pragma unroll
        for (int dy = 0; dy < 3; ++dy) {
            int yin = clamp63(y + dy - 1);
            float r0[6], r1[6];
            load_row6(p0 + yin * 64, xq, r0);
            load_row6(p1 + yin * 64, xq, r1);
            #pragma unroll
            for (int dz = 0; dz < 3; ++dz) {
                int zo = zi - dz;
                if (zo >= 0 && zo < 4) {
                    #pragma unroll
                    for (int dx = 0; dx < 3; ++dx) {
                        float w0v = w[dz * 9 + dy * 3 + dx];
                        float w1v = w[27 + dz * 9 + dy * 3 + dx];
                        #pragma unroll
                        for (int xx = 0; xx < 4; ++xx) {
                            acc[zo][xx] = fmaf(w0v, r0[xx + dx], acc[zo][xx]);
                            acc[zo][xx] = fmaf(w1v, r1[xx + dx], acc[zo][xx]);
                        }
                    }
                }
            }
        }
    }
    float bv = *bias;
    float* obase = out + (size_t)b * 262144 + (size_t)z0 * 4096 + y * 64 + xq;
    #pragma unroll
    for (int zo = 0; zo < 4; ++zo) {
        float4 o;
        o.x = softsign(acc[zo][0] + bv);
        o.y = softsign(acc[zo][1] + bv);
        o.z = softsign(acc[zo][2] + bv);
        o.w = softsign(acc[zo][3] + bv);
        *(float4*)(obase + zo * 4096) = o;
    }
}

// ---- middle layer, occupancy-tiled: 64x * 8y * 8z per block ----
// LDS: 10 planes (z0-1..z0+8 cl) x 10 rows (y0-1..y0+8 cl) x stride 68 = 27.2 KB
// -> 4 blocks/CU co-resident (grid 1024 = 4 x 256 CUs), 16 waves/CU, 2x the
// latency-hiding of the 49KB/2-block round-0 tile. VGPR capped at 128 via
// __launch_bounds__(256,4); acc is [4][4] so no spill pressure.
// Grid 1024 = 8 z-slabs (XCD-affine via blk&7) x 16 batches x 8 y-tiles.
// Thread = (4x, 1y, 4z): l=t&15 -> xq, g=t>>4: yloc=g&7, zh=(g>>3)*4.
#define LROW   68
#define LPLANE 680    // 10*68

__global__ __launch_bounds__(256, 4) void conv_mid(const float* __restrict__ in,
                                                   float* __restrict__ out,
                                                   const float* __restrict__ w,
                                                   const float* __restrict__ bias) {
    __shared__ float lds[10 * LPLANE];

    int blk = blockIdx.x;
    int xcd = blk & 7;
    int j   = blk >> 3;                // 0..127
    int b   = j & 15;
    int y0  = ((j >> 4) & 7) << 3;     // 0,8,...,56
    int z0  = xcd << 3;                // XCD-affine z-slab

    int t = threadIdx.x;
    int l = t & 15;
    int g = t >> 4;

    const float* base = in + (size_t)b * 262144;

    float wv[27];
    #pragma unroll
    for (int i = 0; i < 27; ++i) wv[i] = w[i];
    float bv = *bias;

    // ---- stage 100 rows (10 planes x 10 rows); batched loads, guarded writes ----
    // Shifted x layout (round-0 verbatim): pos p holds x=p-1; dups at 0,64,65.
    {
        int off = (l == 0) ? 0 : (4 * l - 1);
        float* lrows[7]; f4u mv[7]; float tv[7];
        #pragma unroll
        for (int it = 0; it < 7; ++it) {
            int rid = it * 16 + g;                 // 0..111 (100..111 dummy)
            int pa = rid / 10;
            pa = pa > 9 ? 9 : pa;                  // dummy rows: clamp-safe addr
            int pr = rid - pa * 10;
            pr = pr > 9 ? 9 : pr;
            const float* grow = base + clamp63(z0 - 1 + pa) * 4096 + clamp63(y0 - 1 + pr) * 64;
            lrows[it] = &lds[pa * LPLANE + pr * LROW];
            mv[it] = *(const f4u*)(grow + off);
            tv[it] = grow[63];
        }
        #pragma unroll
        for (int it = 0; it < 7; ++it) {
            int rid = it * 16 + g;
            if (rid < 100) {
                if (l == 0)
                    *(float4*)lrows[it] = (float4){mv[it].x, mv[it].x, mv[it].y, mv[it].z};
                else
                    *(float4*)(lrows[it] + 4 * l) = (float4){mv[it].x, mv[it].y, mv[it].z, mv[it].w};
                if (l == 15)
                    *(float2*)(lrows[it] + 64) = (float2){tv[it], tv[it]};
            }
        }
    }
    __syncthreads();

    // ---- compute: 4z x 1y x 4x per thread ----
    int xq   = l << 2;
    int yloc = g & 7;              // 0..7; LDS rows yloc..yloc+2 = y-1,y,y+1
    int zh   = (g >> 3) << 2;      // 0 or 4

    float acc[4][4];
    #pragma unroll
    for (int i = 0; i < 4; ++i)
        #pragma unroll
        for (int k = 0; k < 4; ++k) acc[i][k] = 0.0f;

    #pragma unroll
    for (int pp = 0; pp < 6; ++pp) {
        const float* pl = &lds[(zh + pp) * LPLANE];
        #pragma unroll
        for (int dy = 0; dy < 3; ++dy) {
            const float* lrow = pl + (yloc + dy) * LROW;
            const float4 v  = *(const float4*)(lrow + xq);
            const float2 v2 = *(const float2*)(lrow + xq + 4);
            float r[6] = {v.x, v.y, v.z, v.w, v2.x, v2.y};
            #pragma unroll
            for (int dz = 0; dz < 3; ++dz) {
                int zz = pp - dz;              // output z (local to half), planes pa=zh+zz+dz
                if (zz >= 0 && zz < 4) {
                    #pragma unroll
                    for (int dx = 0; dx < 3; ++dx) {
                        float ww = wv[dz * 9 + dy * 3 + dx];
                        #pragma unroll
                        for (int xx = 0; xx < 4; ++xx)
                            acc[zz][xx] = fmaf(ww, r[xx + dx], acc[zz][xx]);
                    }
                }
            }
        }
    }

    int y = y0 + yloc;
    float* obase = out + (size_t)b * 262144 + (size_t)(z0 + zh) * 4096 + y * 64 + xq;
    #pragma unroll
    for (int zz = 0; zz < 4; ++zz) {
        float4 o;
        o.x = softsign(acc[zz][0] + bv);
        o.y = softsign(acc[zz][1] + bv);
        o.z = softsign(acc[zz][2] + bv);
        o.w = softsign(acc[zz][3] + bv);
        *(float4*)(obase + zz * 4096) = o;   // normal store: stays in local-XCD L2
    }
}

// -------- last layer: 1 -> 3 channels + strided downsample outputs (round-0 verbatim) --------
__global__ __launch_bounds__(256) void conv_last(const float* __restrict__ in,
                                                 float* __restrict__ out,
                                                 const float* __restrict__ w,
                                                 const float* __restrict__ bias) {
    int tid = blockIdx.x * 256 + threadIdx.x;
    int xq = (tid & 15) << 2;
    int y  = (tid >> 4) & 63;
    int z0 = ((tid >> 10) & 15) << 2;
    int b  = tid >> 14;
    const float* base = in + (size_t)b * 262144;

    float acc[4][3][4];
    #pragma unroll
    for (int i = 0; i < 4; ++i)
        #pragma unroll
        for (int c = 0; c < 3; ++c)
            #pragma unroll
            for (int j = 0; j < 4; ++j) acc[i][c][j] = 0.0f;

    #pragma unroll
    for (int zi = 0; zi < 6; ++zi) {
        int zin = clamp63(z0 + zi - 1);
        const float* plane = base + zin * 4096;
        #pragma unroll
        for (int dy = 0; dy < 3; ++dy) {
            int yin = clamp63(y + dy - 1);
            float r[6];
            load_row6(plane + yin * 64, xq, r);
            #pragma unroll
            for (int dz = 0; dz < 3; ++dz) {
                int zo = zi - dz;
                if (zo >= 0 && zo < 4) {
                    #pragma unroll
                    for (int c = 0; c < 3; ++c) {
                        #pragma unroll
                        for (int dx = 0; dx < 3; ++dx) {
                            float wc = w[c * 27 + dz * 9 + dy * 3 + dx];
                            #pragma unroll
                            for (int xx = 0; xx < 4; ++xx)
                                acc[zo][c][xx] = fmaf(wc, r[xx + dx], acc[zo][c][xx]);
                        }
                    }
                }
            }
        }
    }

    float* r64 = out;
    float* r32 = out + 12582912;
    float* r16 = r32 + 1572864;
    float* r8  = r16 + 196608;

    float vals[4][3][4];
    #pragma unroll
    for (int zo = 0; zo < 4; ++zo)
        #pragma unroll
        for (int c = 0; c < 3; ++c) {
            float bv = bias[c];
            #pragma unroll
            for (int xx = 0; xx < 4; ++xx)
                vals[zo][c][xx] = softsign(acc[zo][c][xx] + bv);
        }

    #pragma unroll
    for (int c = 0; c < 3; ++c) {
        float* cb = r64 + ((size_t)b * 3 + c) * 262144 + (size_t)z0 * 4096 + y * 64 + xq;
        #pragma unroll
        for (int zo = 0; zo < 4; ++zo) {
            nt_store4(cb + zo * 4096,
                      vals[zo][c][0], vals[zo][c][1], vals[zo][c][2], vals[zo][c][3]);
        }
    }
    if ((y & 1) == 0) {
        #pragma unroll
        for (int c = 0; c < 3; ++c) {
            size_t cb = ((size_t)b * 3 + c) * 32768 + (size_t)(y >> 1) * 32;
            #pragma unroll
            for (int zo = 0; zo < 4; zo += 2) {
                size_t zb = cb + (size_t)((z0 + zo) >> 1) * 1024;
                __builtin_nontemporal_store(vals[zo][c][0], r32 + zb + ((xq + 0) >> 1));
                __builtin_nontemporal_store(vals[zo][c][2], r32 + zb + ((xq + 2) >> 1));
            }
        }
    }
    if ((y & 3) == 0) {
        #pragma unroll
        for (int c = 0; c < 3; ++c) {
            __builtin_nontemporal_store(vals[0][c][0],
                r16 + ((size_t)b * 3 + c) * 4096 + (size_t)(z0 >> 2) * 256 + (y >> 2) * 16 + (xq >> 2));
        }
    }
    if ((y & 7) == 0 && (z0 & 7) == 0 && (xq & 7) == 0) {
        #pragma unroll
        for (int c = 0; c < 3; ++c) {
            __builtin_nontemporal_store(vals[0][c][0],
                r8 + ((size_t)b * 3 + c) * 512 + (size_t)(z0 >> 3) * 64 + (y >> 3) * 8 + (xq >> 3));
        }
    }
}

extern "C" void kernel_launch(void* const* d_in, const int* in_sizes, int n_in,
                              void* d_out, int out_size, void* d_ws, size_t ws_size,
                              hipStream_t stream) {
    const float* preop = (const float*)d_in[0];
    const float* intra = (const float*)d_in[1];
    const float* w0    = (const float*)d_in[2];
    const float* b0p   = (const float*)d_in[3];
    const float* wsp   = (const float*)d_in[4];
    const float* bsp   = (const float*)d_in[5];
    const float* wX    = (const float*)d_in[6];
    const float* bX    = (const float*)d_in[7];
    float* out = (float*)d_out;

    float* buf0 = (float*)d_ws;
    float* buf1 = out;   // ping-pong scratch inside the (larger) output buffer

    conv_first<<<dim3(1024), dim3(256), 0, stream>>>(preop, intra, buf0, w0, b0p);
    for (int i = 0; i < 100; ++i) {
        const float* src = (i & 1) ? buf1 : buf0;
        float* dst       = (i & 1) ? buf0 : buf1;
        conv_mid<<<dim3(1024), dim3(256), 0, stream>>>(src, dst, wsp + i * 27, bsp + i);
    }
    conv_last<<<dim3(1024), dim3(256), 0, stream>>>(buf0, out, wX, bX);
}

// Round 8
// 944.560 us; speedup vs baseline: 7.9871x; 1.2357x over previous
//
#include <hip/hip_runtime.h>
#include <math.h>

typedef float f4u __attribute__((ext_vector_type(4), aligned(4)));
typedef float nfloat4 __attribute__((ext_vector_type(4), aligned(16)));
typedef _Float16 h16;
typedef _Float16 h4 __attribute__((ext_vector_type(4)));   // 8B
typedef _Float16 h2 __attribute__((ext_vector_type(2)));   // 4B

__device__ __forceinline__ float softsign(float v) {
    float d = 1.0f + fabsf(v);
    return v * __builtin_amdgcn_rcpf(d);
}
__device__ __forceinline__ void nt_store4(float* p, float a, float b, float c, float d) {
    nfloat4 v; v.x = a; v.y = b; v.z = c; v.w = d;
    __builtin_nontemporal_store(v, (nfloat4*)p);
}
__device__ __forceinline__ int clamp63(int v) { return v < 0 ? 0 : (v > 63 ? 63 : v); }

// -------- first layer: 2 fp32 input channels -> 1 fp16 channel --------
__global__ __launch_bounds__(256) void conv_first(const float* __restrict__ in0,
                                                  const float* __restrict__ in1,
                                                  h16* __restrict__ out,
                                                  const float* __restrict__ w,
                                                  const float* __restrict__ bias) {
    int tid = blockIdx.x * 256 + threadIdx.x;
    int xq = (tid & 15) << 2;
    int y  = (tid >> 4) & 63;
    int z0 = ((tid >> 10) & 15) << 2;
    int b  = tid >> 14;
    const float* base0 = in0 + (size_t)b * 262144;
    const float* base1 = in1 + (size_t)b * 262144;

    float acc[4][4];
    #pragma unroll
    for (int i = 0; i < 4; ++i)
        #pragma unroll
        for (int j = 0; j < 4; ++j) acc[i][j] = 0.0f;

    #pragma unroll
    for (int zi = 0; zi < 6; ++zi) {
        int zin = clamp63(z0 + zi - 1);
        const float* p0 = base0 + zin * 4096;
        const float* p1 = base1 + zin * 4096;
        #pragma unroll
        for (int dy = 0; dy < 3; ++dy) {
            int yin = clamp63(y + dy - 1);
            const float* r0p = p0 + yin * 64;
            const float* r1p = p1 + yin * 64;
            float r0[6], r1[6];
            {
                const float4 v = *(const float4*)(r0p + xq);
                r0[0] = r0p[xq == 0 ? 0 : xq - 1];
                r0[1] = v.x; r0[2] = v.y; r0[3] = v.z; r0[4] = v.w;
                r0[5] = r0p[xq == 60 ? 63 : xq + 4];
            }
            {
                const float4 v = *(const float4*)(r1p + xq);
                r1[0] = r1p[xq == 0 ? 0 : xq - 1];
                r1[1] = v.x; r1[2] = v.y; r1[3] = v.z; r1[4] = v.w;
                r1[5] = r1p[xq == 60 ? 63 : xq + 4];
            }
            #pragma unroll
            for (int dz = 0; dz < 3; ++dz) {
                int zo = zi - dz;
                if (zo >= 0 && zo < 4) {
                    #pragma unroll
                    for (int dx = 0; dx < 3; ++dx) {
                        float w0v = w[dz * 9 + dy * 3 + dx];
                        float w1v = w[27 + dz * 9 + dy * 3 + dx];
                        #pragma unroll
                        for (int xx = 0; xx < 4; ++xx) {
                            acc[zo][xx] = fmaf(w0v, r0[xx + dx], acc[zo][xx]);
                            acc[zo][xx] = fmaf(w1v, r1[xx + dx], acc[zo][xx]);
                        }
                    }
                }
            }
        }
    }
    float bv = *bias;
    h16* obase = out + (size_t)b * 262144 + (size_t)z0 * 4096 + y * 64 + xq;
    #pragma unroll
    for (int zo = 0; zo < 4; ++zo) {
        h4 o;
        o.x = (h16)softsign(acc[zo][0] + bv);
        o.y = (h16)softsign(acc[zo][1] + bv);
        o.z = (h16)softsign(acc[zo][2] + bv);
        o.w = (h16)softsign(acc[zo][3] + bv);
        *(h4*)(obase + zo * 4096) = o;
    }
}

// ---- middle layer, fp16 storage / fp32 math: 64x * 8y * 8z per block ----
// LDS: 10 planes x 10 rows x 68 halves = 13.6 KB. Grid 1024 = 4 blocks/CU
// (round-7 verified mapping: 8 XCD z-slabs x 16 batches x 8 y-tiles).
// LDS layout UNSHIFTED (position p = x), dup at position 64 = row[63];
// x-1 neighbor read as hi half of the aligned h2 at xq-2 (select for lane 0).
// All h4 accesses 8B-aligned: row stride 136B, offsets 8*l.
#define LROWH   68
#define LPLANEH 680    // 10*68

__global__ __launch_bounds__(256, 4) void conv_mid(const h16* __restrict__ in,
                                                   h16* __restrict__ out,
                                                   const float* __restrict__ w,
                                                   const float* __restrict__ bias) {
    __shared__ h16 lds[10 * LPLANEH];

    int blk = blockIdx.x;
    int xcd = blk & 7;
    int j   = blk >> 3;                // 0..127
    int b   = j & 15;
    int y0  = ((j >> 4) & 7) << 3;     // 0,8,...,56
    int z0  = xcd << 3;                // XCD-affine z-slab

    int t = threadIdx.x;
    int l = t & 15;
    int g = t >> 4;

    const h16* base = in + (size_t)b * 262144;

    float wv[27];
    #pragma unroll
    for (int i = 0; i < 27; ++i) wv[i] = w[i];
    float bv = *bias;

    // ---- stage 100 rows (10 planes x 10 rows); raw half moves, no converts ----
    {
        h16* lrows[7]; h4 mv[7]; h16 tv[7];
        #pragma unroll
        for (int it = 0; it < 7; ++it) {
            int rid = it * 16 + g;                 // 0..111 (100..111 dummy)
            int pa = rid / 10;
            pa = pa > 9 ? 9 : pa;                  // dummy rows: clamp-safe addr
            int pr = rid - pa * 10;
            pr = pr > 9 ? 9 : pr;
            const h16* grow = base + clamp63(z0 - 1 + pa) * 4096 + clamp63(y0 - 1 + pr) * 64;
            lrows[it] = &lds[pa * LPLANEH + pr * LROWH];
            mv[it] = *(const h4*)(grow + 4 * l);   // x = 4l..4l+3, 8B-aligned
            tv[it] = grow[63];
        }
        #pragma unroll
        for (int it = 0; it < 7; ++it) {
            int rid = it * 16 + g;
            if (rid < 100) {
                *(h4*)(lrows[it] + 4 * l) = mv[it];
                if (l == 15) { h2 d; d.x = tv[it]; d.y = tv[it]; *(h2*)(lrows[it] + 64) = d; }
            }
        }
    }
    __syncthreads();

    // ---- compute (fp32 math): 4z x 1y x 4x per thread ----
    int xq   = l << 2;
    int yloc = g & 7;              // 0..7; LDS rows yloc..yloc+2 = y-1,y,y+1
    int zh   = (g >> 3) << 2;      // 0 or 4

    float acc[4][4];
    #pragma unroll
    for (int i = 0; i < 4; ++i)
        #pragma unroll
        for (int k = 0; k < 4; ++k) acc[i][k] = 0.0f;

    #pragma unroll
    for (int pp = 0; pp < 6; ++pp) {
        const h16* pl = &lds[(zh + pp) * LPLANEH];
        #pragma unroll
        for (int dy = 0; dy < 3; ++dy) {
            const h16* lrow = pl + (yloc + dy) * LROWH;
            h4 v  = *(const h4*)(lrow + xq);                     // x = xq..xq+3
            h2 v2 = *(const h2*)(lrow + xq + 4);                 // x = xq+4, xq+5
            h2 vf = *(const h2*)(lrow + (xq == 0 ? 0 : xq - 2)); // hi = x = xq-1
            float r[6];
            r[0] = (xq == 0) ? (float)v.x : (float)vf.y;
            r[1] = (float)v.x; r[2] = (float)v.y; r[3] = (float)v.z;
            r[4] = (float)v.w; r[5] = (float)v2.x;
            #pragma unroll
            for (int dz = 0; dz < 3; ++dz) {
                int zz = pp - dz;
                if (zz >= 0 && zz < 4) {
                    #pragma unroll
                    for (int dx = 0; dx < 3; ++dx) {
                        float ww = wv[dz * 9 + dy * 3 + dx];
                        #pragma unroll
                        for (int xx = 0; xx < 4; ++xx)
                            acc[zz][xx] = fmaf(ww, r[xx + dx], acc[zz][xx]);
                    }
                }
            }
        }
    }

    int y = y0 + yloc;
    h16* obase = out + (size_t)b * 262144 + (size_t)(z0 + zh) * 4096 + y * 64 + xq;
    #pragma unroll
    for (int zz = 0; zz < 4; ++zz) {
        h4 o;
        o.x = (h16)softsign(acc[zz][0] + bv);
        o.y = (h16)softsign(acc[zz][1] + bv);
        o.z = (h16)softsign(acc[zz][2] + bv);
        o.w = (h16)softsign(acc[zz][3] + bv);
        *(h4*)(obase + zz * 4096) = o;   // normal store: stays in local-XCD L2
    }
}

// -------- last layer: fp16 in -> 3 fp32 channels + strided downsamples --------
__device__ __forceinline__ void load_row6h(const h16* __restrict__ row, int x0, float r[6]) {
    h4 v = *(const h4*)(row + x0);
    r[0] = (float)row[x0 == 0 ? 0 : x0 - 1];
    r[1] = (float)v.x; r[2] = (float)v.y; r[3] = (float)v.z; r[4] = (float)v.w;
    r[5] = (float)row[x0 == 60 ? 63 : x0 + 4];
}

__global__ __launch_bounds__(256) void conv_last(const h16* __restrict__ in,
                                                 float* __restrict__ out,
                                                 const float* __restrict__ w,
                                                 const float* __restrict__ bias) {
    int tid = blockIdx.x * 256 + threadIdx.x;
    int xq = (tid & 15) << 2;
    int y  = (tid >> 4) & 63;
    int z0 = ((tid >> 10) & 15) << 2;
    int b  = tid >> 14;
    const h16* base = in + (size_t)b * 262144;

    float acc[4][3][4];
    #pragma unroll
    for (int i = 0; i < 4; ++i)
        #pragma unroll
        for (int c = 0; c < 3; ++c)
            #pragma unroll
            for (int j = 0; j < 4; ++j) acc[i][c][j] = 0.0f;

    #pragma unroll
    for (int zi = 0; zi < 6; ++zi) {
        int zin = clamp63(z0 + zi - 1);
        const h16* plane = base + zin * 4096;
        #pragma unroll
        for (int dy = 0; dy < 3; ++dy) {
            int yin = clamp63(y + dy - 1);
            float r[6];
            load_row6h(plane + yin * 64, xq, r);
            #pragma unroll
            for (int dz = 0; dz < 3; ++dz) {
                int zo = zi - dz;
                if (zo >= 0 && zo < 4) {
                    #pragma unroll
                    for (int c = 0; c < 3; ++c) {
                        #pragma unroll
                        for (int dx = 0; dx < 3; ++dx) {
                            float wc = w[c * 27 + dz * 9 + dy * 3 + dx];
                            #pragma unroll
                            for (int xx = 0; xx < 4; ++xx)
                                acc[zo][c][xx] = fmaf(wc, r[xx + dx], acc[zo][c][xx]);
                        }
                    }
                }
            }
        }
    }

    float* r64 = out;
    float* r32 = out + 12582912;
    float* r16 = r32 + 1572864;
    float* r8  = r16 + 196608;

    float vals[4][3][4];
    #pragma unroll
    for (int zo = 0; zo < 4; ++zo)
        #pragma unroll
        for (int c = 0; c < 3; ++c) {
            float bv = bias[c];
            #pragma unroll
            for (int xx = 0; xx < 4; ++xx)
                vals[zo][c][xx] = softsign(acc[zo][c][xx] + bv);
        }

    #pragma unroll
    for (int c = 0; c < 3; ++c) {
        float* cb = r64 + ((size_t)b * 3 + c) * 262144 + (size_t)z0 * 4096 + y * 64 + xq;
        #pragma unroll
        for (int zo = 0; zo < 4; ++zo) {
            nt_store4(cb + zo * 4096,
                      vals[zo][c][0], vals[zo][c][1], vals[zo][c][2], vals[zo][c][3]);
        }
    }
    if ((y & 1) == 0) {
        #pragma unroll
        for (int c = 0; c < 3; ++c) {
            size_t cb = ((size_t)b * 3 + c) * 32768 + (size_t)(y >> 1) * 32;
            #pragma unroll
            for (int zo = 0; zo < 4; zo += 2) {
                size_t zb = cb + (size_t)((z0 + zo) >> 1) * 1024;
                __builtin_nontemporal_store(vals[zo][c][0], r32 + zb + ((xq + 0) >> 1));
                __builtin_nontemporal_store(vals[zo][c][2], r32 + zb + ((xq + 2) >> 1));
            }
        }
    }
    if ((y & 3) == 0) {
        #pragma unroll
        for (int c = 0; c < 3; ++c) {
            __builtin_nontemporal_store(vals[0][c][0],
                r16 + ((size_t)b * 3 + c) * 4096 + (size_t)(z0 >> 2) * 256 + (y >> 2) * 16 + (xq >> 2));
        }
    }
    if ((y & 7) == 0 && (z0 & 7) == 0 && (xq & 7) == 0) {
        #pragma unroll
        for (int c = 0; c < 3; ++c) {
            __builtin_nontemporal_store(vals[0][c][0],
                r8 + ((size_t)b * 3 + c) * 512 + (size_t)(z0 >> 3) * 64 + (y >> 3) * 8 + (xq >> 3));
        }
    }
}

extern "C" void kernel_launch(void* const* d_in, const int* in_sizes, int n_in,
                              void* d_out, int out_size, void* d_ws, size_t ws_size,
                              hipStream_t stream) {
    const float* preop = (const float*)d_in[0];
    const float* intra = (const float*)d_in[1];
    const float* w0    = (const float*)d_in[2];
    const float* b0p   = (const float*)d_in[3];
    const float* wsp   = (const float*)d_in[4];
    const float* bsp   = (const float*)d_in[5];
    const float* wX    = (const float*)d_in[6];
    const float* bX    = (const float*)d_in[7];
    float* out = (float*)d_out;

    h16* buf0 = (h16*)d_ws;          // 8.4 MB fp16 ping
    h16* buf1 = (h16*)out;           // fp16 pong inside the (larger) output buffer;
                                     // conv_last never reads buf1, so no aliasing hazard.

    conv_first<<<dim3(1024), dim3(256), 0, stream>>>(preop, intra, buf0, w0, b0p);
    for (int i = 0; i < 100; ++i) {
        const h16* src = (i & 1) ? buf1 : buf0;
        h16* dst       = (i & 1) ? buf0 : buf1;
        conv_mid<<<dim3(1024), dim3(256), 0, stream>>>(src, dst, wsp + i * 27, bsp + i);
    }
    conv_last<<<dim3(1024), dim3(256), 0, stream>>>(buf0, out, wX, bX);
}